// Round 1
// baseline (1281.497 us; speedup 1.0000x reference)
//
#include <hip/hip_runtime.h>

typedef float f32x4 __attribute__((ext_vector_type(4)));
typedef short bfrag __attribute__((ext_vector_type(8)));
typedef short sh4 __attribute__((ext_vector_type(4)));

__device__ __forceinline__ unsigned short f2bf(float x) {
  unsigned int u = __float_as_uint(x);
  return (unsigned short)((u + 0x7FFFu + ((u >> 16) & 1u)) >> 16);
}
__device__ __forceinline__ float bf2f(unsigned short u) {
  return __uint_as_float(((unsigned int)u) << 16);
}
__device__ __forceinline__ float wred_sum(float v) {
#pragma unroll
  for (int o = 32; o > 0; o >>= 1) v += __shfl_xor(v, o);
  return v;
}
__device__ __forceinline__ float wred_max(float v) {
#pragma unroll
  for (int o = 32; o > 0; o >>= 1) v = fmaxf(v, __shfl_xor(v, o));
  return v;
}

// ---------------------------------------------------------------------------
// Phase A: partial[b][ks][m][c] = sum_{k in chunk} hard(mask[b][m][k]) * feat[b][c][k]
// M=112 (100 padded), Ntile=128 (ct=0/1), K-split 16 x 1024. bf16 MFMA 16x16x32.
// ---------------------------------------------------------------------------
__global__ __launch_bounds__(256) void phaseA(const float* __restrict__ mask,
                                              const float* __restrict__ feat,
                                              float* __restrict__ partial) {
  int tid = threadIdx.x;
  int ks = blockIdx.x;  // 0..15
  int ct = blockIdx.y;  // 0..1
  int b  = blockIdx.z;  // 0..7
  __shared__ short Al[112 * 136];
  __shared__ short Bl[128 * 136];
  int w = tid >> 6, lane = tid & 63, quad = lane >> 4, l15 = lane & 15;

  f32x4 acc[7][2];
#pragma unroll
  for (int mt = 0; mt < 7; ++mt)
#pragma unroll
    for (int nt = 0; nt < 2; ++nt) {
      acc[mt][nt][0] = 0.f; acc[mt][nt][1] = 0.f; acc[mt][nt][2] = 0.f; acc[mt][nt][3] = 0.f;
    }

  int k0 = ks * 1024;
  for (int st = 0; st < 8; ++st) {
    int kb = k0 + st * 128;
    // stage A: 112 rows x 128 k, binarized bf16
#pragma unroll
    for (int p = 0; p < 14; ++p) {
      int flat = p * 256 + tid;       // float4 units, 0..3583
      int row = flat >> 5, c4 = flat & 31;
      sh4 o4;
      if (row < 100) {
        float4 v = *(const float4*)(mask + (size_t)(b * 100 + row) * 16384 + kb + c4 * 4);
        o4[0] = (v.x > 0.f) ? (short)0x3F80 : (short)0;
        o4[1] = (v.y > 0.f) ? (short)0x3F80 : (short)0;
        o4[2] = (v.z > 0.f) ? (short)0x3F80 : (short)0;
        o4[3] = (v.w > 0.f) ? (short)0x3F80 : (short)0;
      } else {
        o4[0] = 0; o4[1] = 0; o4[2] = 0; o4[3] = 0;
      }
      *(sh4*)(Al + row * 136 + c4 * 4) = o4;
    }
    // stage B: 128 c-rows x 128 k, fp32 -> bf16
#pragma unroll
    for (int p = 0; p < 16; ++p) {
      int flat = p * 256 + tid;       // 0..4095
      int row = flat >> 5, c4 = flat & 31;
      float4 v = *(const float4*)(feat + (size_t)(b * 256 + ct * 128 + row) * 16384 + kb + c4 * 4);
      sh4 o4;
      o4[0] = (short)f2bf(v.x); o4[1] = (short)f2bf(v.y);
      o4[2] = (short)f2bf(v.z); o4[3] = (short)f2bf(v.w);
      *(sh4*)(Bl + row * 136 + c4 * 4) = o4;
    }
    __syncthreads();
#pragma unroll
    for (int kk = 0; kk < 4; ++kk) {
      bfrag av[7], bv[2];
#pragma unroll
      for (int mt = 0; mt < 7; ++mt)
        av[mt] = *(const bfrag*)(Al + (mt * 16 + l15) * 136 + kk * 32 + quad * 8);
#pragma unroll
      for (int nt = 0; nt < 2; ++nt)
        bv[nt] = *(const bfrag*)(Bl + (w * 32 + nt * 16 + l15) * 136 + kk * 32 + quad * 8);
#pragma unroll
      for (int mt = 0; mt < 7; ++mt) {
        acc[mt][0] = __builtin_amdgcn_mfma_f32_16x16x32_bf16(av[mt], bv[0], acc[mt][0], 0, 0, 0);
        acc[mt][1] = __builtin_amdgcn_mfma_f32_16x16x32_bf16(av[mt], bv[1], acc[mt][1], 0, 0, 0);
      }
    }
    __syncthreads();
  }
  float* pb = partial + (size_t)(b * 16 + ks) * (112 * 256) + ct * 128;
#pragma unroll
  for (int mt = 0; mt < 7; ++mt)
#pragma unroll
    for (int nt = 0; nt < 2; ++nt)
#pragma unroll
      for (int r = 0; r < 4; ++r) {
        int m = mt * 16 + quad * 4 + r;
        int c = w * 32 + nt * 16 + l15;
        pb[(size_t)m * 256 + c] = acc[mt][nt][r];
      }
}

__global__ __launch_bounds__(256) void reduceA(const float* __restrict__ partial,
                                               float* __restrict__ fm) {
  int gid = blockIdx.x * 256 + threadIdx.x;  // < 204800
  int c = gid & 255, row = gid >> 8;         // row < 800
  int b = row / 100, n = row % 100;
  float s = 0.f;
#pragma unroll
  for (int ks = 0; ks < 16; ++ks)
    s += partial[((size_t)(b * 16 + ks) * 112 + n) * 256 + c];
  fm[(size_t)row * 256 + c] = s;
}

// ---------------------------------------------------------------------------
// Generic row-wise GEMM: C[r][col] = act(sum_k A[r][k]*W[k][col] + bias[col])
// A: [800][K] (K multiple of 64), W: [K][N]. Block: 32 rows x 64 cols.
// ---------------------------------------------------------------------------
__global__ __launch_bounds__(256) void gemm_rw(const float* __restrict__ A,
                                               const float* __restrict__ W,
                                               const float* __restrict__ bias,
                                               float* __restrict__ C,
                                               int K, int N, int relu) {
  __shared__ float Al[32 * 68];
  int tid = threadIdx.x;
  int r0 = blockIdx.x * 32;
  int c0 = blockIdx.y * 64;
  int cg = tid & 63, rg = tid >> 6;
  int col = c0 + cg;
  int colc = (col < N) ? col : (N - 1);
  float acc[8];
#pragma unroll
  for (int i = 0; i < 8; ++i) acc[i] = 0.f;

  for (int k0 = 0; k0 < K; k0 += 64) {
#pragma unroll
    for (int p = 0; p < 2; ++p) {
      int flat = p * 256 + tid;          // float4 id 0..511
      int row = flat >> 4, c4 = flat & 15;
      float4 v = *(const float4*)(A + (size_t)(r0 + row) * K + k0 + c4 * 4);
      *(float4*)(Al + row * 68 + c4 * 4) = v;
    }
    __syncthreads();
    const float* wp = W + (size_t)k0 * N + colc;
#pragma unroll 4
    for (int kk = 0; kk < 64; kk += 4) {
      float w0 = wp[(size_t)(kk + 0) * N];
      float w1 = wp[(size_t)(kk + 1) * N];
      float w2 = wp[(size_t)(kk + 2) * N];
      float w3 = wp[(size_t)(kk + 3) * N];
#pragma unroll
      for (int i = 0; i < 8; ++i) {
        float4 av = *(const float4*)(Al + (rg * 8 + i) * 68 + kk);
        acc[i] += av.x * w0 + av.y * w1 + av.z * w2 + av.w * w3;
      }
    }
    __syncthreads();
  }
  if (col < N) {
    float bv = bias ? bias[col] : 0.f;
#pragma unroll
    for (int i = 0; i < 8; ++i) {
      float v = acc[i] + bv;
      if (relu) v = fmaxf(v, 0.f);
      C[(size_t)(r0 + rg * 8 + i) * N + col] = v;
    }
  }
}

// ---------------------------------------------------------------------------
// dysep middle: depth (3-tap conv over channels, relu) + point = pw @ depth
// wbuf rows: [dw0 dw1 dw2 | pw(100)] (103 floats). grid (8 cgroups, 8 b).
// ---------------------------------------------------------------------------
__global__ __launch_bounds__(256) void pointdw(const float* __restrict__ fm,
                                               const float* __restrict__ wbuf,
                                               float* __restrict__ point) {
  int tid = threadIdx.x;
  int b = blockIdx.y, c0 = blockIdx.x * 32;
  __shared__ float dl[100 * 33];
  for (int flat = tid; flat < 3200; flat += 256) {
    int n = flat >> 5, cl = flat & 31, c = c0 + cl;
    const float* fr = fm + (size_t)(b * 100 + n) * 256;
    const float* wr = wbuf + (size_t)(b * 100 + n) * 103;
    float x0 = (c > 0) ? fr[c - 1] : 0.f;
    float x1 = fr[c];
    float x2 = (c < 255) ? fr[c + 1] : 0.f;
    float d = wr[0] * x0 + wr[1] * x1 + wr[2] * x2;
    dl[n * 33 + cl] = fmaxf(d, 0.f);
  }
  __syncthreads();
  int cl = tid & 31, mg = tid >> 5;
  for (int m = mg; m < 100; m += 8) {
    const float* pw = wbuf + (size_t)(b * 100 + m) * 103 + 3;
    float a = 0.f;
#pragma unroll 4
    for (int n = 0; n < 100; ++n) a += pw[n] * dl[n * 33 + cl];
    point[(size_t)(b * 100 + m) * 256 + c0 + cl] = a;
  }
}

// ---------------------------------------------------------------------------
// ln2: out = LN( resid + LN(x)*g1+b1 ) * g2 + b2   (wave per row, 4 rows/block)
// ---------------------------------------------------------------------------
__global__ __launch_bounds__(256) void ln2_kernel(const float* __restrict__ x,
                                                  const float* __restrict__ resid,
                                                  const float* __restrict__ g1, const float* __restrict__ b1,
                                                  const float* __restrict__ g2, const float* __restrict__ b2,
                                                  float* __restrict__ out) {
  int tid = threadIdx.x;
  int row = blockIdx.x * 4 + (tid >> 6);
  int lane = tid & 63;
  size_t base = (size_t)row * 256 + lane * 4;
  float4 v = *(const float4*)(x + base);
  float mean = wred_sum(v.x + v.y + v.z + v.w) * (1.f / 256.f);
  float d0 = v.x - mean, d1 = v.y - mean, d2 = v.z - mean, d3 = v.w - mean;
  float rs = rsqrtf(wred_sum(d0 * d0 + d1 * d1 + d2 * d2 + d3 * d3) * (1.f / 256.f) + 1e-5f);
  float4 gv = *(const float4*)(g1 + lane * 4);
  float4 bv = *(const float4*)(b1 + lane * 4);
  float4 rv = *(const float4*)(resid + base);
  float y0 = rv.x + d0 * rs * gv.x + bv.x;
  float y1 = rv.y + d1 * rs * gv.y + bv.y;
  float y2 = rv.z + d2 * rs * gv.z + bv.z;
  float y3 = rv.w + d3 * rs * gv.w + bv.w;
  float mean2 = wred_sum(y0 + y1 + y2 + y3) * (1.f / 256.f);
  float e0 = y0 - mean2, e1 = y1 - mean2, e2 = y2 - mean2, e3 = y3 - mean2;
  float rs2 = rsqrtf(wred_sum(e0 * e0 + e1 * e1 + e2 * e2 + e3 * e3) * (1.f / 256.f) + 1e-5f);
  float4 g2v = *(const float4*)(g2 + lane * 4);
  float4 b2v = *(const float4*)(b2 + lane * 4);
  float4 o;
  o.x = e0 * rs2 * g2v.x + b2v.x;
  o.y = e1 * rs2 * g2v.y + b2v.y;
  o.z = e2 * rs2 * g2v.z + b2v.z;
  o.w = e3 * rs2 * g2v.w + b2v.w;
  *(float4*)(out + base) = o;
}

// ln: out = act( LN(x [+res]) * g + b ), optional duplicate write to copy2
__global__ __launch_bounds__(256) void ln_kernel(const float* __restrict__ x,
                                                 const float* __restrict__ res,
                                                 const float* __restrict__ g, const float* __restrict__ bb,
                                                 float* __restrict__ out, int relu,
                                                 float* __restrict__ copy2) {
  int tid = threadIdx.x;
  int row = blockIdx.x * 4 + (tid >> 6);
  int lane = tid & 63;
  size_t base = (size_t)row * 256 + lane * 4;
  float4 v = *(const float4*)(x + base);
  if (res) {
    float4 rv = *(const float4*)(res + base);
    v.x += rv.x; v.y += rv.y; v.z += rv.z; v.w += rv.w;
  }
  float mean = wred_sum(v.x + v.y + v.z + v.w) * (1.f / 256.f);
  float d0 = v.x - mean, d1 = v.y - mean, d2 = v.z - mean, d3 = v.w - mean;
  float rs = rsqrtf(wred_sum(d0 * d0 + d1 * d1 + d2 * d2 + d3 * d3) * (1.f / 256.f) + 1e-5f);
  float4 gv = *(const float4*)(g + lane * 4);
  float4 bv = *(const float4*)(bb + lane * 4);
  float4 o;
  o.x = d0 * rs * gv.x + bv.x;
  o.y = d1 * rs * gv.y + bv.y;
  o.z = d2 * rs * gv.z + bv.z;
  o.w = d3 * rs * gv.w + bv.w;
  if (relu) {
    o.x = fmaxf(o.x, 0.f); o.y = fmaxf(o.y, 0.f);
    o.z = fmaxf(o.z, 0.f); o.w = fmaxf(o.w, 0.f);
  }
  *(float4*)(out + base) = o;
  if (copy2) *(float4*)(copy2 + base) = o;
}

// ---------------------------------------------------------------------------
// MHA: one block per (head, batch). N=100, d=32.
// ---------------------------------------------------------------------------
__global__ __launch_bounds__(256) void attn_kernel(const float* __restrict__ qkv,
                                                   float* __restrict__ obuf) {
  int tid = threadIdx.x;
  int b = blockIdx.y, h = blockIdx.x;
  __shared__ float kt[32 * 100];          // k^T [dd][j]
  __shared__ unsigned short vl[100 * 32]; // v bf16 [j][dd]
  __shared__ float sl[100 * 100];         // scores / probs
  const float* base = qkv + (size_t)b * 100 * 768;
  for (int flat = tid; flat < 3200; flat += 256) {
    int j = flat >> 5, dd = flat & 31;
    kt[dd * 100 + j] = base[(size_t)j * 768 + 256 + h * 32 + dd];
    vl[j * 32 + dd] = f2bf(base[(size_t)j * 768 + 512 + h * 32 + dd]);
  }
  __syncthreads();
  for (int flat = tid; flat < 10000; flat += 256) {
    int i = flat / 100, j = flat % 100;
    const float4* q4 = (const float4*)(base + (size_t)i * 768 + h * 32);
    float a = 0.f;
#pragma unroll
    for (int d4 = 0; d4 < 8; ++d4) {
      float4 qv = q4[d4];
      a += qv.x * kt[(d4 * 4 + 0) * 100 + j];
      a += qv.y * kt[(d4 * 4 + 1) * 100 + j];
      a += qv.z * kt[(d4 * 4 + 2) * 100 + j];
      a += qv.w * kt[(d4 * 4 + 3) * 100 + j];
    }
    sl[i * 100 + j] = a * 0.17677669529663687f;  // 1/sqrt(32)
  }
  __syncthreads();
  int w = tid >> 6, lane = tid & 63;
  for (int r = w; r < 100; r += 4) {
    float x0 = sl[r * 100 + lane];
    float x1 = (lane + 64 < 100) ? sl[r * 100 + lane + 64] : -1e30f;
    float mx = wred_max(fmaxf(x0, x1));
    float e0 = __expf(x0 - mx);
    float e1 = (lane + 64 < 100) ? __expf(x1 - mx) : 0.f;
    float inv = 1.f / wred_sum(e0 + e1);
    sl[r * 100 + lane] = e0 * inv;
    if (lane + 64 < 100) sl[r * 100 + lane + 64] = e1 * inv;
  }
  __syncthreads();
  for (int flat = tid; flat < 3200; flat += 256) {
    int i = flat >> 5, dd = flat & 31;
    float a = 0.f;
#pragma unroll 4
    for (int j = 0; j < 100; ++j) a += sl[i * 100 + j] * bf2f(vl[j * 32 + dd]);
    obuf[(size_t)(b * 100 + i) * 256 + h * 32 + dd] = a;
  }
}

// ---------------------------------------------------------------------------
// Phase E: out[b][q][hw] = sum_c mk[b][q][c] * feat[b][c][hw]
// A (mk) staged once in LDS bf16; B fragments read directly from global fp32.
// ---------------------------------------------------------------------------
__global__ __launch_bounds__(256) void phaseE(const float* __restrict__ mk,
                                              const float* __restrict__ feat,
                                              float* __restrict__ out) {
  int tid = threadIdx.x;
  int b = blockIdx.y;
  int hw0 = blockIdx.x * 128;
  __shared__ short Al[112 * 264];
#pragma unroll
  for (int p = 0; p < 28; ++p) {
    int flat = p * 256 + tid;  // float4 units 0..7167
    int row = flat >> 6, c4 = flat & 63;
    sh4 o4;
    if (row < 100) {
      float4 v = *(const float4*)(mk + (size_t)(b * 100 + row) * 256 + c4 * 4);
      o4[0] = (short)f2bf(v.x); o4[1] = (short)f2bf(v.y);
      o4[2] = (short)f2bf(v.z); o4[3] = (short)f2bf(v.w);
    } else {
      o4[0] = 0; o4[1] = 0; o4[2] = 0; o4[3] = 0;
    }
    *(sh4*)(Al + row * 264 + c4 * 4) = o4;
  }
  __syncthreads();
  int w = tid >> 6, lane = tid & 63, quad = lane >> 4, l15 = lane & 15;
  f32x4 acc[7][2];
#pragma unroll
  for (int mt = 0; mt < 7; ++mt)
#pragma unroll
    for (int nt = 0; nt < 2; ++nt) {
      acc[mt][nt][0] = 0.f; acc[mt][nt][1] = 0.f; acc[mt][nt][2] = 0.f; acc[mt][nt][3] = 0.f;
    }
  size_t fb = (size_t)b * 256 * 16384;
  int hwl = hw0 + w * 32 + l15;
  for (int kk = 0; kk < 8; ++kk) {
    bfrag bv[2];
#pragma unroll
    for (int nt = 0; nt < 2; ++nt) {
#pragma unroll
      for (int j = 0; j < 8; ++j) {
        float v = feat[fb + (size_t)(kk * 32 + quad * 8 + j) * 16384 + hwl + nt * 16];
        bv[nt][j] = (short)f2bf(v);
      }
    }
    bfrag av[7];
#pragma unroll
    for (int mt = 0; mt < 7; ++mt)
      av[mt] = *(const bfrag*)(Al + (mt * 16 + l15) * 264 + kk * 32 + quad * 8);
#pragma unroll
    for (int mt = 0; mt < 7; ++mt) {
      acc[mt][0] = __builtin_amdgcn_mfma_f32_16x16x32_bf16(av[mt], bv[0], acc[mt][0], 0, 0, 0);
      acc[mt][1] = __builtin_amdgcn_mfma_f32_16x16x32_bf16(av[mt], bv[1], acc[mt][1], 0, 0, 0);
    }
  }
#pragma unroll
  for (int mt = 0; mt < 7; ++mt)
#pragma unroll
    for (int nt = 0; nt < 2; ++nt)
#pragma unroll
      for (int r = 0; r < 4; ++r) {
        int m = mt * 16 + quad * 4 + r;
        if (m < 100)
          out[(size_t)(b * 100 + m) * 16384 + hw0 + w * 32 + nt * 16 + l15] = acc[mt][nt][r];
      }
}

// ---------------------------------------------------------------------------
extern "C" void kernel_launch(void* const* d_in, const int* in_sizes, int n_in,
                              void* d_out, int out_size, void* d_ws, size_t ws_size,
                              hipStream_t stream) {
  const float* feat    = (const float*)d_in[0];
  const float* prop    = (const float*)d_in[1];
  const float* maskp   = (const float*)d_in[2];
  const float* fW      = (const float*)d_in[3];
  const float* fb_     = (const float*)d_in[4];
  const float* fng     = (const float*)d_in[5];
  const float* fnb     = (const float*)d_in[6];
  const float* f_ng    = (const float*)d_in[7];
  const float* f_nb    = (const float*)d_in[8];
  const float* kW      = (const float*)d_in[9];
  const float* kb_     = (const float*)d_in[10];
  const float* kng     = (const float*)d_in[11];
  const float* knb     = (const float*)d_in[12];
  const float* k_ng    = (const float*)d_in[13];
  const float* k_nb    = (const float*)d_in[14];
  const float* aw_in   = (const float*)d_in[15];
  const float* ab_in   = (const float*)d_in[16];
  const float* aw_out  = (const float*)d_in[17];
  const float* ab_out  = (const float*)d_in[18];
  const float* s_ng    = (const float*)d_in[19];
  const float* s_nb    = (const float*)d_in[20];
  const float* w1      = (const float*)d_in[21];
  const float* b1      = (const float*)d_in[22];
  const float* w2      = (const float*)d_in[23];
  const float* b2      = (const float*)d_in[24];
  const float* ffn_ng  = (const float*)d_in[25];
  const float* ffn_nb  = (const float*)d_in[26];
  const float* cls_w   = (const float*)d_in[27];
  const float* cls_g   = (const float*)d_in[28];
  const float* cls_b   = (const float*)d_in[29];
  const float* fcclsw  = (const float*)d_in[30];
  const float* fcclsb  = (const float*)d_in[31];
  const float* mask_w  = (const float*)d_in[32];
  const float* mask_g  = (const float*)d_in[33];
  const float* mask_b  = (const float*)d_in[34];
  const float* fcmw    = (const float*)d_in[35];
  const float* fcmb    = (const float*)d_in[36];
  float* out = (float*)d_out;

  float* ws = (float*)d_ws;
  size_t off = 0;
  float* partial = ws + off; off += (size_t)8 * 16 * 112 * 256;  // 3,670,016
  float* fm   = ws + off; off += 204800;
  float* wb   = ws + off; off += 82400;
  float* pt   = ws + off; off += 204800;
  float* fbuf = ws + off; off += 204800;
  float* kkb  = ws + off; off += 204800;
  float* qkvb = ws + off; off += 614400;
  float* ob   = ws + off; off += 204800;
  float* mo   = ws + off; off += 204800;
  float* kk2  = ws + off; off += 204800;
  float* ffn1 = ws + off; off += 1638400;
  float* t1   = ws + off; off += 204800;
  float* objb = ws + off; off += 204800;
  float* t2   = ws + off; off += 204800;
  float* mkb  = ws + off; off += 204800;

  float* out_cls  = out;                       // [800][81]
  float* out_mask = out + 64800;               // [8][100][16384]
  float* out_obj  = out + 64800 + 13107200;    // [800][256]

  // f_masked = hard(mask) @ feat^T
  phaseA<<<dim3(16, 2, 8), 256, 0, stream>>>(maskp, feat, partial);
  reduceA<<<800, 256, 0, stream>>>(partial, fm);
  // dysep 1
  gemm_rw<<<dim3(25, 2), 256, 0, stream>>>(prop, fW, fb_, wb, 256, 103, 0);
  pointdw<<<dim3(8, 8), 256, 0, stream>>>(fm, wb, pt);
  ln2_kernel<<<200, 256, 0, stream>>>(pt, fm, fng, fnb, f_ng, f_nb, fbuf);
  // dysep 2
  gemm_rw<<<dim3(25, 2), 256, 0, stream>>>(prop, kW, kb_, wb, 256, 103, 0);
  pointdw<<<dim3(8, 8), 256, 0, stream>>>(fbuf, wb, pt);
  ln2_kernel<<<200, 256, 0, stream>>>(pt, fbuf, kng, knb, k_ng, k_nb, kkb);
  // MHA
  gemm_rw<<<dim3(25, 12), 256, 0, stream>>>(kkb, aw_in, ab_in, qkvb, 256, 768, 0);
  attn_kernel<<<dim3(8, 8), 256, 0, stream>>>(qkvb, ob);
  gemm_rw<<<dim3(25, 4), 256, 0, stream>>>(ob, aw_out, ab_out, mo, 256, 256, 0);
  ln_kernel<<<200, 256, 0, stream>>>(mo, kkb, s_ng, s_nb, kk2, 0, nullptr);
  // FFN
  gemm_rw<<<dim3(25, 32), 256, 0, stream>>>(kk2, w1, b1, ffn1, 256, 2048, 1);
  gemm_rw<<<dim3(25, 4), 256, 0, stream>>>(ffn1, w2, b2, t1, 2048, 256, 0);
  ln_kernel<<<200, 256, 0, stream>>>(t1, kk2, ffn_ng, ffn_nb, objb, 0, out_obj);
  // cls head
  gemm_rw<<<dim3(25, 4), 256, 0, stream>>>(objb, cls_w, nullptr, t1, 256, 256, 0);
  ln_kernel<<<200, 256, 0, stream>>>(t1, nullptr, cls_g, cls_b, t2, 1, nullptr);
  gemm_rw<<<dim3(25, 2), 256, 0, stream>>>(t2, fcclsw, fcclsb, out_cls, 256, 81, 0);
  // mask head (3 layers)
  gemm_rw<<<dim3(25, 4), 256, 0, stream>>>(objb, mask_w, nullptr, t1, 256, 256, 0);
  ln_kernel<<<200, 256, 0, stream>>>(t1, nullptr, mask_g, mask_b, t2, 1, nullptr);
  gemm_rw<<<dim3(25, 4), 256, 0, stream>>>(t2, mask_w + 65536, nullptr, t1, 256, 256, 0);
  ln_kernel<<<200, 256, 0, stream>>>(t1, nullptr, mask_g + 256, mask_b + 256, t2, 1, nullptr);
  gemm_rw<<<dim3(25, 4), 256, 0, stream>>>(t2, mask_w + 131072, nullptr, t1, 256, 256, 0);
  ln_kernel<<<200, 256, 0, stream>>>(t1, nullptr, mask_g + 512, mask_b + 512, t2, 1, nullptr);
  gemm_rw<<<dim3(25, 4), 256, 0, stream>>>(t2, fcmw, fcmb, mkb, 256, 256, 0);
  // new_mask_preds = mk @ feat
  phaseE<<<dim3(128, 8), 256, 0, stream>>>(mkb, feat, out_mask);
}

// Round 3
// 802.961 us; speedup vs baseline: 1.5960x; 1.5960x over previous
//
#include <hip/hip_runtime.h>

typedef float f32x4 __attribute__((ext_vector_type(4)));
typedef short bfrag __attribute__((ext_vector_type(8)));
typedef short sh4 __attribute__((ext_vector_type(4)));

__device__ __forceinline__ unsigned short f2bf(float x) {
  unsigned int u = __float_as_uint(x);
  return (unsigned short)((u + 0x7FFFu + ((u >> 16) & 1u)) >> 16);
}
__device__ __forceinline__ float bf2f(unsigned short u) {
  return __uint_as_float(((unsigned int)u) << 16);
}
__device__ __forceinline__ float wred_sum(float v) {
#pragma unroll
  for (int o = 32; o > 0; o >>= 1) v += __shfl_xor(v, o);
  return v;
}
__device__ __forceinline__ float wred_max(float v) {
#pragma unroll
  for (int o = 32; o > 0; o >>= 1) v = fmaxf(v, __shfl_xor(v, o));
  return v;
}

// ---------------------------------------------------------------------------
// Weight prep: Wt[n][k] (bf16, k-contiguous) = W[k][n] for 12 weight matrices.
// ---------------------------------------------------------------------------
struct Prep12 {
  const float* s[12];
  int K[12];
  int N[12];
  int base[12];
  int doff[12];
};

__global__ __launch_bounds__(256) void prep_w(Prep12 p, unsigned short* wt) {
  int t = blockIdx.x;
  int wi = 0;
#pragma unroll
  for (int i = 0; i < 11; ++i)
    if (t >= p.base[i + 1]) wi = i + 1;
  int lt = t - p.base[wi];
  int K = p.K[wi], N = p.N[wi];
  int tkn = (K + 31) >> 5;
  int tk = lt % tkn, tn = lt / tkn;
  __shared__ float tile[32][33];
  const float* src = p.s[wi];
#pragma unroll
  for (int i = 0; i < 4; ++i) {
    int flat = i * 256 + threadIdx.x;
    int kl = flat >> 5, nl = flat & 31;
    int k = tk * 32 + kl, n = tn * 32 + nl;
    tile[kl][nl] = (k < K && n < N) ? src[(size_t)k * N + n] : 0.f;
  }
  __syncthreads();
  unsigned short* dst = wt + p.doff[wi];
#pragma unroll
  for (int i = 0; i < 4; ++i) {
    int flat = i * 256 + threadIdx.x;
    int nl = flat >> 5, kl = flat & 31;
    int k = tk * 32 + kl, n = tn * 32 + nl;
    if (k < K && n < N) dst[(size_t)n * K + k] = f2bf(tile[kl][nl]);
  }
}

// ---------------------------------------------------------------------------
// MFMA GEMM: C[m][n] = act(sum_k A[m][k] * Wt[n][k] + bias[n])
// ---------------------------------------------------------------------------
template <int ABF, int OBF>
__global__ __launch_bounds__(256) void gemm_mf(const void* Av,
                                               const unsigned short* __restrict__ Wt,
                                               const float* __restrict__ bias,
                                               void* Cv, int M, int K, int N, int relu) {
  __shared__ short Al[64 * 72];
  __shared__ short Wl[64 * 72];
  int tid = threadIdx.x;
  int r0 = blockIdx.x * 64;
  int c0 = blockIdx.y * 64;
  int w = tid >> 6, lane = tid & 63, quad = lane >> 4, l15 = lane & 15;

  f32x4 acc[4];
#pragma unroll
  for (int mt = 0; mt < 4; ++mt) {
    acc[mt][0] = 0.f; acc[mt][1] = 0.f; acc[mt][2] = 0.f; acc[mt][3] = 0.f;
  }

  for (int k0 = 0; k0 < K; k0 += 64) {
    if (ABF) {
      const unsigned short* A = (const unsigned short*)Av;
#pragma unroll
      for (int p = 0; p < 2; ++p) {
        int flat = p * 256 + tid;
        int row = flat >> 3, k8 = flat & 7;
        bfrag v;
        if (r0 + row < M)
          v = *(const bfrag*)(A + (size_t)(r0 + row) * K + k0 + k8 * 8);
        else
          v = (bfrag)(short)0;
        *(bfrag*)(Al + row * 72 + k8 * 8) = v;
      }
    } else {
      const float* A = (const float*)Av;
#pragma unroll
      for (int p = 0; p < 4; ++p) {
        int flat = p * 256 + tid;
        int row = flat >> 4, c4 = flat & 15;
        sh4 o4;
        if (r0 + row < M) {
          float4 v = *(const float4*)(A + (size_t)(r0 + row) * K + k0 + c4 * 4);
          o4[0] = (short)f2bf(v.x); o4[1] = (short)f2bf(v.y);
          o4[2] = (short)f2bf(v.z); o4[3] = (short)f2bf(v.w);
        } else {
          o4[0] = 0; o4[1] = 0; o4[2] = 0; o4[3] = 0;
        }
        *(sh4*)(Al + row * 72 + c4 * 4) = o4;
      }
    }
#pragma unroll
    for (int p = 0; p < 2; ++p) {
      int flat = p * 256 + tid;
      int row = flat >> 3, k8 = flat & 7;
      bfrag v;
      if (c0 + row < N)
        v = *(const bfrag*)(Wt + (size_t)(c0 + row) * K + k0 + k8 * 8);
      else
        v = (bfrag)(short)0;
      *(bfrag*)(Wl + row * 72 + k8 * 8) = v;
    }
    __syncthreads();
#pragma unroll
    for (int kk = 0; kk < 2; ++kk) {
      bfrag bv = *(const bfrag*)(Wl + (w * 16 + l15) * 72 + kk * 32 + quad * 8);
#pragma unroll
      for (int mt = 0; mt < 4; ++mt) {
        bfrag av = *(const bfrag*)(Al + (mt * 16 + l15) * 72 + kk * 32 + quad * 8);
        acc[mt] = __builtin_amdgcn_mfma_f32_16x16x32_bf16(av, bv, acc[mt], 0, 0, 0);
      }
    }
    __syncthreads();
  }
  int col = c0 + w * 16 + l15;
  if (col < N) {
    float bv = bias ? bias[col] : 0.f;
#pragma unroll
    for (int mt = 0; mt < 4; ++mt)
#pragma unroll
      for (int r = 0; r < 4; ++r) {
        int m = r0 + mt * 16 + quad * 4 + r;
        if (m < M) {
          float v = acc[mt][r] + bv;
          if (relu) v = fmaxf(v, 0.f);
          if (OBF)
            ((unsigned short*)Cv)[(size_t)m * N + col] = f2bf(v);
          else
            ((float*)Cv)[(size_t)m * N + col] = v;
        }
      }
  }
}

// ---------------------------------------------------------------------------
// Phase A
// ---------------------------------------------------------------------------
__global__ __launch_bounds__(256) void phaseA(const float* __restrict__ mask,
                                              const float* __restrict__ feat,
                                              float* __restrict__ partial) {
  int tid = threadIdx.x;
  int ks = blockIdx.x;
  int ct = blockIdx.y;
  int b  = blockIdx.z;
  __shared__ short Al[112 * 136];
  __shared__ short Bl[128 * 136];
  int w = tid >> 6, lane = tid & 63, quad = lane >> 4, l15 = lane & 15;

  f32x4 acc[7][2];
#pragma unroll
  for (int mt = 0; mt < 7; ++mt)
#pragma unroll
    for (int nt = 0; nt < 2; ++nt) {
      acc[mt][nt][0] = 0.f; acc[mt][nt][1] = 0.f; acc[mt][nt][2] = 0.f; acc[mt][nt][3] = 0.f;
    }

  int k0 = ks * 1024;
  for (int st = 0; st < 8; ++st) {
    int kb = k0 + st * 128;
#pragma unroll
    for (int p = 0; p < 14; ++p) {
      int flat = p * 256 + tid;
      int row = flat >> 5, c4 = flat & 31;
      sh4 o4;
      if (row < 100) {
        float4 v = *(const float4*)(mask + (size_t)(b * 100 + row) * 16384 + kb + c4 * 4);
        o4[0] = (v.x > 0.f) ? (short)0x3F80 : (short)0;
        o4[1] = (v.y > 0.f) ? (short)0x3F80 : (short)0;
        o4[2] = (v.z > 0.f) ? (short)0x3F80 : (short)0;
        o4[3] = (v.w > 0.f) ? (short)0x3F80 : (short)0;
      } else {
        o4[0] = 0; o4[1] = 0; o4[2] = 0; o4[3] = 0;
      }
      *(sh4*)(Al + row * 136 + c4 * 4) = o4;
    }
#pragma unroll
    for (int p = 0; p < 16; ++p) {
      int flat = p * 256 + tid;
      int row = flat >> 5, c4 = flat & 31;
      float4 v = *(const float4*)(feat + (size_t)(b * 256 + ct * 128 + row) * 16384 + kb + c4 * 4);
      sh4 o4;
      o4[0] = (short)f2bf(v.x); o4[1] = (short)f2bf(v.y);
      o4[2] = (short)f2bf(v.z); o4[3] = (short)f2bf(v.w);
      *(sh4*)(Bl + row * 136 + c4 * 4) = o4;
    }
    __syncthreads();
#pragma unroll
    for (int kk = 0; kk < 4; ++kk) {
      bfrag av[7], bv[2];
#pragma unroll
      for (int mt = 0; mt < 7; ++mt)
        av[mt] = *(const bfrag*)(Al + (mt * 16 + l15) * 136 + kk * 32 + quad * 8);
#pragma unroll
      for (int nt = 0; nt < 2; ++nt)
        bv[nt] = *(const bfrag*)(Bl + (w * 32 + nt * 16 + l15) * 136 + kk * 32 + quad * 8);
#pragma unroll
      for (int mt = 0; mt < 7; ++mt) {
        acc[mt][0] = __builtin_amdgcn_mfma_f32_16x16x32_bf16(av[mt], bv[0], acc[mt][0], 0, 0, 0);
        acc[mt][1] = __builtin_amdgcn_mfma_f32_16x16x32_bf16(av[mt], bv[1], acc[mt][1], 0, 0, 0);
      }
    }
    __syncthreads();
  }
  float* pb = partial + (size_t)(b * 16 + ks) * (112 * 256) + ct * 128;
#pragma unroll
  for (int mt = 0; mt < 7; ++mt)
#pragma unroll
    for (int nt = 0; nt < 2; ++nt)
#pragma unroll
      for (int r = 0; r < 4; ++r) {
        int m = mt * 16 + quad * 4 + r;
        int c = w * 32 + nt * 16 + l15;
        pb[(size_t)m * 256 + c] = acc[mt][nt][r];
      }
}

__global__ __launch_bounds__(256) void reduceA(const float* __restrict__ partial,
                                               float* __restrict__ fm) {
  int gid = blockIdx.x * 256 + threadIdx.x;
  int c = gid & 255, row = gid >> 8;
  int b = row / 100, n = row % 100;
  float s = 0.f;
#pragma unroll
  for (int ks = 0; ks < 16; ++ks)
    s += partial[((size_t)(b * 16 + ks) * 112 + n) * 256 + c];
  fm[(size_t)row * 256 + c] = s;
}

// ---------------------------------------------------------------------------
// dysep middle
// ---------------------------------------------------------------------------
__global__ __launch_bounds__(256) void pointdw(const float* __restrict__ fm,
                                               const float* __restrict__ wbuf,
                                               float* __restrict__ point) {
  int tid = threadIdx.x;
  int b = blockIdx.y, c0 = blockIdx.x * 32;
  __shared__ float dl[100 * 33];
  for (int flat = tid; flat < 3200; flat += 256) {
    int n = flat >> 5, cl = flat & 31, c = c0 + cl;
    const float* fr = fm + (size_t)(b * 100 + n) * 256;
    const float* wr = wbuf + (size_t)(b * 100 + n) * 103;
    float x0 = (c > 0) ? fr[c - 1] : 0.f;
    float x1 = fr[c];
    float x2 = (c < 255) ? fr[c + 1] : 0.f;
    float d = wr[0] * x0 + wr[1] * x1 + wr[2] * x2;
    dl[n * 33 + cl] = fmaxf(d, 0.f);
  }
  __syncthreads();
  int cl = tid & 31, mg = tid >> 5;
  for (int m = mg; m < 100; m += 8) {
    const float* pw = wbuf + (size_t)(b * 100 + m) * 103 + 3;
    float a = 0.f;
#pragma unroll 4
    for (int n = 0; n < 100; ++n) a += pw[n] * dl[n * 33 + cl];
    point[(size_t)(b * 100 + m) * 256 + c0 + cl] = a;
  }
}

// ---------------------------------------------------------------------------
__global__ __launch_bounds__(256) void ln2_kernel(const float* __restrict__ x,
                                                  const float* __restrict__ resid,
                                                  const float* __restrict__ g1, const float* __restrict__ b1,
                                                  const float* __restrict__ g2, const float* __restrict__ b2,
                                                  float* __restrict__ out) {
  int tid = threadIdx.x;
  int row = blockIdx.x * 4 + (tid >> 6);
  int lane = tid & 63;
  size_t base = (size_t)row * 256 + lane * 4;
  float4 v = *(const float4*)(x + base);
  float mean = wred_sum(v.x + v.y + v.z + v.w) * (1.f / 256.f);
  float d0 = v.x - mean, d1 = v.y - mean, d2 = v.z - mean, d3 = v.w - mean;
  float rs = rsqrtf(wred_sum(d0 * d0 + d1 * d1 + d2 * d2 + d3 * d3) * (1.f / 256.f) + 1e-5f);
  float4 gv = *(const float4*)(g1 + lane * 4);
  float4 bv = *(const float4*)(b1 + lane * 4);
  float4 rv = *(const float4*)(resid + base);
  float y0 = rv.x + d0 * rs * gv.x + bv.x;
  float y1 = rv.y + d1 * rs * gv.y + bv.y;
  float y2 = rv.z + d2 * rs * gv.z + bv.z;
  float y3 = rv.w + d3 * rs * gv.w + bv.w;
  float mean2 = wred_sum(y0 + y1 + y2 + y3) * (1.f / 256.f);
  float e0 = y0 - mean2, e1 = y1 - mean2, e2 = y2 - mean2, e3 = y3 - mean2;
  float rs2 = rsqrtf(wred_sum(e0 * e0 + e1 * e1 + e2 * e2 + e3 * e3) * (1.f / 256.f) + 1e-5f);
  float4 g2v = *(const float4*)(g2 + lane * 4);
  float4 b2v = *(const float4*)(b2 + lane * 4);
  float4 o;
  o.x = e0 * rs2 * g2v.x + b2v.x;
  o.y = e1 * rs2 * g2v.y + b2v.y;
  o.z = e2 * rs2 * g2v.z + b2v.z;
  o.w = e3 * rs2 * g2v.w + b2v.w;
  *(float4*)(out + base) = o;
}

__global__ __launch_bounds__(256) void ln_kernel(const float* __restrict__ x,
                                                 const float* __restrict__ res,
                                                 const float* __restrict__ g, const float* __restrict__ bb,
                                                 float* __restrict__ out, int relu,
                                                 float* __restrict__ copy2) {
  int tid = threadIdx.x;
  int row = blockIdx.x * 4 + (tid >> 6);
  int lane = tid & 63;
  size_t base = (size_t)row * 256 + lane * 4;
  float4 v = *(const float4*)(x + base);
  if (res) {
    float4 rv = *(const float4*)(res + base);
    v.x += rv.x; v.y += rv.y; v.z += rv.z; v.w += rv.w;
  }
  float mean = wred_sum(v.x + v.y + v.z + v.w) * (1.f / 256.f);
  float d0 = v.x - mean, d1 = v.y - mean, d2 = v.z - mean, d3 = v.w - mean;
  float rs = rsqrtf(wred_sum(d0 * d0 + d1 * d1 + d2 * d2 + d3 * d3) * (1.f / 256.f) + 1e-5f);
  float4 gv = *(const float4*)(g + lane * 4);
  float4 bv = *(const float4*)(bb + lane * 4);
  float4 o;
  o.x = d0 * rs * gv.x + bv.x;
  o.y = d1 * rs * gv.y + bv.y;
  o.z = d2 * rs * gv.z + bv.z;
  o.w = d3 * rs * gv.w + bv.w;
  if (relu) {
    o.x = fmaxf(o.x, 0.f); o.y = fmaxf(o.y, 0.f);
    o.z = fmaxf(o.z, 0.f); o.w = fmaxf(o.w, 0.f);
  }
  *(float4*)(out + base) = o;
  if (copy2) *(float4*)(copy2 + base) = o;
}

// ---------------------------------------------------------------------------
// MHA
// ---------------------------------------------------------------------------
__global__ __launch_bounds__(256) void attn_kernel(const float* __restrict__ qkv,
                                                   float* __restrict__ obuf) {
  int tid = threadIdx.x;
  int b = blockIdx.y, h = blockIdx.x;
  __shared__ float kt[32 * 100];
  __shared__ unsigned short vl[100 * 32];
  __shared__ float sl[100 * 100];
  const float* base = qkv + (size_t)b * 100 * 768;
  for (int flat = tid; flat < 3200; flat += 256) {
    int j = flat >> 5, dd = flat & 31;
    kt[dd * 100 + j] = base[(size_t)j * 768 + 256 + h * 32 + dd];
    vl[j * 32 + dd] = f2bf(base[(size_t)j * 768 + 512 + h * 32 + dd]);
  }
  __syncthreads();
  for (int flat = tid; flat < 10000; flat += 256) {
    int i = flat / 100, j = flat % 100;
    const float4* q4 = (const float4*)(base + (size_t)i * 768 + h * 32);
    float a = 0.f;
#pragma unroll
    for (int d4 = 0; d4 < 8; ++d4) {
      float4 qv = q4[d4];
      a += qv.x * kt[(d4 * 4 + 0) * 100 + j];
      a += qv.y * kt[(d4 * 4 + 1) * 100 + j];
      a += qv.z * kt[(d4 * 4 + 2) * 100 + j];
      a += qv.w * kt[(d4 * 4 + 3) * 100 + j];
    }
    sl[i * 100 + j] = a * 0.17677669529663687f;
  }
  __syncthreads();
  int w = tid >> 6, lane = tid & 63;
  for (int r = w; r < 100; r += 4) {
    float x0 = sl[r * 100 + lane];
    float x1 = (lane + 64 < 100) ? sl[r * 100 + lane + 64] : -1e30f;
    float mx = wred_max(fmaxf(x0, x1));
    float e0 = __expf(x0 - mx);
    float e1 = (lane + 64 < 100) ? __expf(x1 - mx) : 0.f;
    float inv = 1.f / wred_sum(e0 + e1);
    sl[r * 100 + lane] = e0 * inv;
    if (lane + 64 < 100) sl[r * 100 + lane + 64] = e1 * inv;
  }
  __syncthreads();
  for (int flat = tid; flat < 3200; flat += 256) {
    int i = flat >> 5, dd = flat & 31;
    float a = 0.f;
#pragma unroll 4
    for (int j = 0; j < 100; ++j) a += sl[i * 100 + j] * bf2f(vl[j * 32 + dd]);
    obuf[(size_t)(b * 100 + i) * 256 + h * 32 + dd] = a;
  }
}

// ---------------------------------------------------------------------------
// Phase E
// ---------------------------------------------------------------------------
__global__ __launch_bounds__(256) void phaseE(const float* __restrict__ mk,
                                              const float* __restrict__ feat,
                                              float* __restrict__ out) {
  int tid = threadIdx.x;
  int b = blockIdx.y;
  int hw0 = blockIdx.x * 128;
  __shared__ short Al[112 * 264];
#pragma unroll
  for (int p = 0; p < 28; ++p) {
    int flat = p * 256 + tid;
    int row = flat >> 6, c4 = flat & 63;
    sh4 o4;
    if (row < 100) {
      float4 v = *(const float4*)(mk + (size_t)(b * 100 + row) * 256 + c4 * 4);
      o4[0] = (short)f2bf(v.x); o4[1] = (short)f2bf(v.y);
      o4[2] = (short)f2bf(v.z); o4[3] = (short)f2bf(v.w);
    } else {
      o4[0] = 0; o4[1] = 0; o4[2] = 0; o4[3] = 0;
    }
    *(sh4*)(Al + row * 264 + c4 * 4) = o4;
  }
  __syncthreads();
  int w = tid >> 6, lane = tid & 63, quad = lane >> 4, l15 = lane & 15;
  f32x4 acc[7][2];
#pragma unroll
  for (int mt = 0; mt < 7; ++mt)
#pragma unroll
    for (int nt = 0; nt < 2; ++nt) {
      acc[mt][nt][0] = 0.f; acc[mt][nt][1] = 0.f; acc[mt][nt][2] = 0.f; acc[mt][nt][3] = 0.f;
    }
  size_t fb = (size_t)b * 256 * 16384;
  int hwl = hw0 + w * 32 + l15;
  for (int kk = 0; kk < 8; ++kk) {
    bfrag bv[2];
#pragma unroll
    for (int nt = 0; nt < 2; ++nt) {
#pragma unroll
      for (int j = 0; j < 8; ++j) {
        float v = feat[fb + (size_t)(kk * 32 + quad * 8 + j) * 16384 + hwl + nt * 16];
        bv[nt][j] = (short)f2bf(v);
      }
    }
    bfrag av[7];
#pragma unroll
    for (int mt = 0; mt < 7; ++mt)
      av[mt] = *(const bfrag*)(Al + (mt * 16 + l15) * 264 + kk * 32 + quad * 8);
#pragma unroll
    for (int mt = 0; mt < 7; ++mt) {
      acc[mt][0] = __builtin_amdgcn_mfma_f32_16x16x32_bf16(av[mt], bv[0], acc[mt][0], 0, 0, 0);
      acc[mt][1] = __builtin_amdgcn_mfma_f32_16x16x32_bf16(av[mt], bv[1], acc[mt][1], 0, 0, 0);
    }
  }
#pragma unroll
  for (int mt = 0; mt < 7; ++mt)
#pragma unroll
    for (int nt = 0; nt < 2; ++nt)
#pragma unroll
      for (int r = 0; r < 4; ++r) {
        int m = mt * 16 + quad * 4 + r;
        if (m < 100)
          out[(size_t)(b * 100 + m) * 16384 + hw0 + w * 32 + nt * 16 + l15] = acc[mt][nt][r];
      }
}

// ---------------------------------------------------------------------------
extern "C" void kernel_launch(void* const* d_in, const int* in_sizes, int n_in,
                              void* d_out, int out_size, void* d_ws, size_t ws_size,
                              hipStream_t stream) {
  const float* feat    = (const float*)d_in[0];
  const float* prop    = (const float*)d_in[1];
  const float* maskp   = (const float*)d_in[2];
  const float* fW      = (const float*)d_in[3];
  const float* fb_     = (const float*)d_in[4];
  const float* fng     = (const float*)d_in[5];
  const float* fnb     = (const float*)d_in[6];
  const float* f_ng    = (const float*)d_in[7];
  const float* f_nb    = (const float*)d_in[8];
  const float* kW      = (const float*)d_in[9];
  const float* kb_     = (const float*)d_in[10];
  const float* kng     = (const float*)d_in[11];
  const float* knb     = (const float*)d_in[12];
  const float* k_ng    = (const float*)d_in[13];
  const float* k_nb    = (const float*)d_in[14];
  const float* aw_in   = (const float*)d_in[15];
  const float* ab_in   = (const float*)d_in[16];
  const float* aw_out  = (const float*)d_in[17];
  const float* ab_out  = (const float*)d_in[18];
  const float* s_ng    = (const float*)d_in[19];
  const float* s_nb    = (const float*)d_in[20];
  const float* w1      = (const float*)d_in[21];
  const float* b1      = (const float*)d_in[22];
  const float* w2      = (const float*)d_in[23];
  const float* b2      = (const float*)d_in[24];
  const float* ffn_ng  = (const float*)d_in[25];
  const float* ffn_nb  = (const float*)d_in[26];
  const float* cls_w   = (const float*)d_in[27];
  const float* cls_g   = (const float*)d_in[28];
  const float* cls_b   = (const float*)d_in[29];
  const float* fcclsw  = (const float*)d_in[30];
  const float* fcclsb  = (const float*)d_in[31];
  const float* mask_w  = (const float*)d_in[32];
  const float* mask_g  = (const float*)d_in[33];
  const float* mask_b  = (const float*)d_in[34];
  const float* fcmw    = (const float*)d_in[35];
  const float* fcmb    = (const float*)d_in[36];
  float* out = (float*)d_out;

  // ---- workspace layout (18.9 MB total; previous 33.2 MB overflowed ws) ----
  // wt (persists whole launch), fm, then a UNION region: `partial` is dead
  // after reduceA, so all later activation buffers alias into its 14.7 MB.
  float* ws = (float*)d_ws;
  size_t off = 0;
  unsigned short* wt = (unsigned short*)(ws + off); off += 855936;  // 1,711,872 bf16
  float* fm      = ws + off; off += 204800;
  float* partial = ws + off;                     // union region: 3,670,016 floats
  {
    size_t u = off;                              // pack smalls inside union
    // total smalls = 3,564,000 <= 3,670,016  (verified)
    off += 3670016;
    (void)u;
  }
  float* ub   = partial;                         // union base
  size_t uo = 0;
  float* wb   = ub + uo; uo += 82400;
  float* pt   = ub + uo; uo += 204800;
  float* fbuf = ub + uo; uo += 204800;
  float* kkb  = ub + uo; uo += 204800;
  float* qkvb = ub + uo; uo += 614400;
  float* ob   = ub + uo; uo += 204800;
  float* mo   = ub + uo; uo += 204800;
  float* kk2  = ub + uo; uo += 204800;
  float* t1   = ub + uo; uo += 204800;
  float* objb = ub + uo; uo += 204800;
  float* t2   = ub + uo; uo += 204800;
  float* mkb  = ub + uo; uo += 204800;
  unsigned short* ffn1b = (unsigned short*)(ub + uo); uo += 819200;  // 800x2048 bf16

  // Wt sub-offsets (shorts)
  const int wt_fW = 0, wt_kW = 26368, wt_ain = 52736, wt_aout = 249344;
  const int wt_w1 = 314880, wt_w2 = 839168, wt_cls = 1363456, wt_fccls = 1428992;
  const int wt_m0 = 1449728, wt_m1 = 1515264, wt_m2 = 1580800, wt_fcm = 1646336;

  float* out_cls  = out;                       // [800][81]
  float* out_mask = out + 64800;               // [8][100][16384]
  float* out_obj  = out + 64800 + 13107200;    // [800][256]

  // ---- weight prep (transpose + bf16) ----
  Prep12 p;
  const float* srcs[12] = {fW, kW, aw_in, aw_out, w1, w2, cls_w, fcclsw,
                           mask_w, mask_w + 65536, mask_w + 131072, fcmw};
  int Ks[12]    = {256, 256, 256, 256, 256, 2048, 256, 256, 256, 256, 256, 256};
  int Ns[12]    = {103, 103, 768, 256, 2048, 256, 256, 81, 256, 256, 256, 256};
  int doffs[12] = {wt_fW, wt_kW, wt_ain, wt_aout, wt_w1, wt_w2, wt_cls, wt_fccls,
                   wt_m0, wt_m1, wt_m2, wt_fcm};
  int tb = 0;
  for (int i = 0; i < 12; ++i) {
    p.s[i] = srcs[i]; p.K[i] = Ks[i]; p.N[i] = Ns[i]; p.doff[i] = doffs[i];
    p.base[i] = tb;
    tb += ((Ks[i] + 31) / 32) * ((Ns[i] + 31) / 32);
  }
  prep_w<<<tb, 256, 0, stream>>>(p, wt);

  // f_masked = hard(mask) @ feat^T
  phaseA<<<dim3(16, 2, 8), 256, 0, stream>>>(maskp, feat, partial);
  reduceA<<<800, 256, 0, stream>>>(partial, fm);
  // dysep 1  (from here on, `partial` region is reused for activations)
  gemm_mf<0, 0><<<dim3(13, 2), 256, 0, stream>>>(prop, wt + wt_fW, fb_, wb, 800, 256, 103, 0);
  pointdw<<<dim3(8, 8), 256, 0, stream>>>(fm, wb, pt);
  ln2_kernel<<<200, 256, 0, stream>>>(pt, fm, fng, fnb, f_ng, f_nb, fbuf);
  // dysep 2
  gemm_mf<0, 0><<<dim3(13, 2), 256, 0, stream>>>(prop, wt + wt_kW, kb_, wb, 800, 256, 103, 0);
  pointdw<<<dim3(8, 8), 256, 0, stream>>>(fbuf, wb, pt);
  ln2_kernel<<<200, 256, 0, stream>>>(pt, fbuf, kng, knb, k_ng, k_nb, kkb);
  // MHA
  gemm_mf<0, 0><<<dim3(13, 12), 256, 0, stream>>>(kkb, wt + wt_ain, ab_in, qkvb, 800, 256, 768, 0);
  attn_kernel<<<dim3(8, 8), 256, 0, stream>>>(qkvb, ob);
  gemm_mf<0, 0><<<dim3(13, 4), 256, 0, stream>>>(ob, wt + wt_aout, ab_out, mo, 800, 256, 256, 0);
  ln_kernel<<<200, 256, 0, stream>>>(mo, kkb, s_ng, s_nb, kk2, 0, nullptr);
  // FFN (ffn1 out bf16; ffn2 consumes bf16 A)
  gemm_mf<0, 1><<<dim3(13, 32), 256, 0, stream>>>(kk2, wt + wt_w1, b1, ffn1b, 800, 256, 2048, 1);
  gemm_mf<1, 0><<<dim3(13, 4), 256, 0, stream>>>(ffn1b, wt + wt_w2, b2, t1, 800, 2048, 256, 0);
  ln_kernel<<<200, 256, 0, stream>>>(t1, kk2, ffn_ng, ffn_nb, objb, 0, out_obj);
  // cls head
  gemm_mf<0, 0><<<dim3(13, 4), 256, 0, stream>>>(objb, wt + wt_cls, nullptr, t1, 800, 256, 256, 0);
  ln_kernel<<<200, 256, 0, stream>>>(t1, nullptr, cls_g, cls_b, t2, 1, nullptr);
  gemm_mf<0, 0><<<dim3(13, 2), 256, 0, stream>>>(t2, wt + wt_fccls, fcclsb, out_cls, 800, 256, 81, 0);
  // mask head (3 layers)
  gemm_mf<0, 0><<<dim3(13, 4), 256, 0, stream>>>(objb, wt + wt_m0, nullptr, t1, 800, 256, 256, 0);
  ln_kernel<<<200, 256, 0, stream>>>(t1, nullptr, mask_g, mask_b, t2, 1, nullptr);
  gemm_mf<0, 0><<<dim3(13, 4), 256, 0, stream>>>(t2, wt + wt_m1, nullptr, t1, 800, 256, 256, 0);
  ln_kernel<<<200, 256, 0, stream>>>(t1, nullptr, mask_g + 256, mask_b + 256, t2, 1, nullptr);
  gemm_mf<0, 0><<<dim3(13, 4), 256, 0, stream>>>(t2, wt + wt_m2, nullptr, t1, 800, 256, 256, 0);
  ln_kernel<<<200, 256, 0, stream>>>(t1, nullptr, mask_g + 512, mask_b + 512, t2, 1, nullptr);
  gemm_mf<0, 0><<<dim3(13, 4), 256, 0, stream>>>(t2, wt + wt_fcm, fcmb, mkb, 800, 256, 256, 0);
  // new_mask_preds = mk @ feat
  phaseE<<<dim3(128, 8), 256, 0, stream>>>(mkb, feat, out_mask);
}

// Round 4
// 681.533 us; speedup vs baseline: 1.8803x; 1.1782x over previous
//
#include <hip/hip_runtime.h>

typedef float f32x4 __attribute__((ext_vector_type(4)));
typedef short bfrag __attribute__((ext_vector_type(8)));
typedef short sh4 __attribute__((ext_vector_type(4)));

__device__ __forceinline__ unsigned short f2bf(float x) {
  unsigned int u = __float_as_uint(x);
  return (unsigned short)((u + 0x7FFFu + ((u >> 16) & 1u)) >> 16);
}
__device__ __forceinline__ float bf2f(unsigned short u) {
  return __uint_as_float(((unsigned int)u) << 16);
}
__device__ __forceinline__ float wred_sum(float v) {
#pragma unroll
  for (int o = 32; o > 0; o >>= 1) v += __shfl_xor(v, o);
  return v;
}
__device__ __forceinline__ float wred_max(float v) {
#pragma unroll
  for (int o = 32; o > 0; o >>= 1) v = fmaxf(v, __shfl_xor(v, o));
  return v;
}

// ---------------------------------------------------------------------------
// Weight prep: Wt[n][k] (bf16, k-contiguous) = W[k][n].
// For wi 0,1 (fW,kW): permute output cols so pw (orig 3..102) lands at rows
// 0..99 and dw (orig 0..2) at rows 100..102 -> pointdw reads pw as float4.
// ---------------------------------------------------------------------------
struct Prep12 {
  const float* s[12];
  int K[12];
  int N[12];
  int base[12];
  int doff[12];
};

__global__ __launch_bounds__(256) void prep_w(Prep12 p, unsigned short* wt) {
  int t = blockIdx.x;
  int wi = 0;
#pragma unroll
  for (int i = 0; i < 11; ++i)
    if (t >= p.base[i + 1]) wi = i + 1;
  int lt = t - p.base[wi];
  int K = p.K[wi], N = p.N[wi];
  int tkn = (K + 31) >> 5;
  int tk = lt % tkn, tn = lt / tkn;
  __shared__ float tile[32][33];
  const float* src = p.s[wi];
#pragma unroll
  for (int i = 0; i < 4; ++i) {
    int flat = i * 256 + threadIdx.x;
    int kl = flat >> 5, nl = flat & 31;
    int k = tk * 32 + kl, n = tn * 32 + nl;
    tile[kl][nl] = (k < K && n < N) ? src[(size_t)k * N + n] : 0.f;
  }
  __syncthreads();
  unsigned short* dst = wt + p.doff[wi];
#pragma unroll
  for (int i = 0; i < 4; ++i) {
    int flat = i * 256 + threadIdx.x;
    int nl = flat >> 5, kl = flat & 31;
    int k = tk * 32 + kl, n = tn * 32 + nl;
    if (k < K && n < N) {
      int np = (wi < 2) ? ((n >= 3) ? n - 3 : n + 100) : n;
      dst[(size_t)np * K + k] = f2bf(tile[kl][nl]);
    }
  }
}

__global__ __launch_bounds__(256) void prep_bias(const float* __restrict__ fb_,
                                                 const float* __restrict__ kb_,
                                                 float* __restrict__ bf,
                                                 float* __restrict__ bk) {
  int t = threadIdx.x;
  if (t < 103) {
    int np = (t >= 3) ? t - 3 : t + 100;
    bf[np] = fb_[t];
    bk[np] = kb_[t];
  }
  if (t == 103) { bf[103] = 0.f; bk[103] = 0.f; }
}

// ---------------------------------------------------------------------------
// MFMA GEMM: C[m][n] = act(sum_k A[m][k] * Wt[n][k] + bias[n]), row stride ldc
// ---------------------------------------------------------------------------
template <int ABF, int OBF>
__global__ __launch_bounds__(256) void gemm_mf(const void* Av,
                                               const unsigned short* __restrict__ Wt,
                                               const float* __restrict__ bias,
                                               void* Cv, int M, int K, int N, int ldc, int relu) {
  __shared__ short Al[64 * 72];
  __shared__ short Wl[64 * 72];
  int tid = threadIdx.x;
  int r0 = blockIdx.x * 64;
  int c0 = blockIdx.y * 64;
  int w = tid >> 6, lane = tid & 63, quad = lane >> 4, l15 = lane & 15;

  f32x4 acc[4];
#pragma unroll
  for (int mt = 0; mt < 4; ++mt) {
    acc[mt][0] = 0.f; acc[mt][1] = 0.f; acc[mt][2] = 0.f; acc[mt][3] = 0.f;
  }

  for (int k0 = 0; k0 < K; k0 += 64) {
    if (ABF) {
      const unsigned short* A = (const unsigned short*)Av;
#pragma unroll
      for (int p = 0; p < 2; ++p) {
        int flat = p * 256 + tid;
        int row = flat >> 3, k8 = flat & 7;
        bfrag v;
        if (r0 + row < M)
          v = *(const bfrag*)(A + (size_t)(r0 + row) * K + k0 + k8 * 8);
        else
          v = (bfrag)(short)0;
        *(bfrag*)(Al + row * 72 + k8 * 8) = v;
      }
    } else {
      const float* A = (const float*)Av;
#pragma unroll
      for (int p = 0; p < 4; ++p) {
        int flat = p * 256 + tid;
        int row = flat >> 4, c4 = flat & 15;
        sh4 o4;
        if (r0 + row < M) {
          float4 v = *(const float4*)(A + (size_t)(r0 + row) * K + k0 + c4 * 4);
          o4[0] = (short)f2bf(v.x); o4[1] = (short)f2bf(v.y);
          o4[2] = (short)f2bf(v.z); o4[3] = (short)f2bf(v.w);
        } else {
          o4[0] = 0; o4[1] = 0; o4[2] = 0; o4[3] = 0;
        }
        *(sh4*)(Al + row * 72 + c4 * 4) = o4;
      }
    }
#pragma unroll
    for (int p = 0; p < 2; ++p) {
      int flat = p * 256 + tid;
      int row = flat >> 3, k8 = flat & 7;
      bfrag v;
      if (c0 + row < N)
        v = *(const bfrag*)(Wt + (size_t)(c0 + row) * K + k0 + k8 * 8);
      else
        v = (bfrag)(short)0;
      *(bfrag*)(Wl + row * 72 + k8 * 8) = v;
    }
    __syncthreads();
#pragma unroll
    for (int kk = 0; kk < 2; ++kk) {
      bfrag bv = *(const bfrag*)(Wl + (w * 16 + l15) * 72 + kk * 32 + quad * 8);
#pragma unroll
      for (int mt = 0; mt < 4; ++mt) {
        bfrag av = *(const bfrag*)(Al + (mt * 16 + l15) * 72 + kk * 32 + quad * 8);
        acc[mt] = __builtin_amdgcn_mfma_f32_16x16x32_bf16(av, bv, acc[mt], 0, 0, 0);
      }
    }
    __syncthreads();
  }
  int col = c0 + w * 16 + l15;
  if (col < N) {
    float bv = bias ? bias[col] : 0.f;
#pragma unroll
    for (int mt = 0; mt < 4; ++mt)
#pragma unroll
      for (int r = 0; r < 4; ++r) {
        int m = r0 + mt * 16 + quad * 4 + r;
        if (m < M) {
          float v = acc[mt][r] + bv;
          if (relu) v = fmaxf(v, 0.f);
          if (OBF)
            ((unsigned short*)Cv)[(size_t)m * ldc + col] = f2bf(v);
          else
            ((float*)Cv)[(size_t)m * ldc + col] = v;
        }
      }
  }
}

// ---------------------------------------------------------------------------
// Phase A: partial[b][ks][m][c] += hard(mask)·feat over K-chunk of 512.
// 512 threads (8 waves); wave w = 16-col strip of the 128-col ct-half.
// ---------------------------------------------------------------------------
__global__ __launch_bounds__(512, 4) void phaseA(const float* __restrict__ mask,
                                                 const float* __restrict__ feat,
                                                 float* __restrict__ partial) {
  int tid = threadIdx.x;
  int ks = blockIdx.x;  // 0..31
  int ct = blockIdx.y;  // 0..1
  int b  = blockIdx.z;  // 0..7
  __shared__ short Al[112 * 136];
  __shared__ short Bl[128 * 136];
  int w = tid >> 6, lane = tid & 63, quad = lane >> 4, l15 = lane & 15;

  f32x4 acc[7];
#pragma unroll
  for (int mt = 0; mt < 7; ++mt) {
    acc[mt][0] = 0.f; acc[mt][1] = 0.f; acc[mt][2] = 0.f; acc[mt][3] = 0.f;
  }

  int k0 = ks * 512;
  for (int st = 0; st < 4; ++st) {
    int kb = k0 + st * 128;
#pragma unroll
    for (int p = 0; p < 7; ++p) {
      int flat = p * 512 + tid;       // float4 units 0..3583
      int row = flat >> 5, c4 = flat & 31;
      sh4 o4;
      if (row < 100) {
        float4 v = *(const float4*)(mask + (size_t)(b * 100 + row) * 16384 + kb + c4 * 4);
        o4[0] = (v.x > 0.f) ? (short)0x3F80 : (short)0;
        o4[1] = (v.y > 0.f) ? (short)0x3F80 : (short)0;
        o4[2] = (v.z > 0.f) ? (short)0x3F80 : (short)0;
        o4[3] = (v.w > 0.f) ? (short)0x3F80 : (short)0;
      } else {
        o4[0] = 0; o4[1] = 0; o4[2] = 0; o4[3] = 0;
      }
      *(sh4*)(Al + row * 136 + c4 * 4) = o4;
    }
#pragma unroll
    for (int p = 0; p < 8; ++p) {
      int flat = p * 512 + tid;       // 0..4095
      int row = flat >> 5, c4 = flat & 31;
      float4 v = *(const float4*)(feat + (size_t)(b * 256 + ct * 128 + row) * 16384 + kb + c4 * 4);
      sh4 o4;
      o4[0] = (short)f2bf(v.x); o4[1] = (short)f2bf(v.y);
      o4[2] = (short)f2bf(v.z); o4[3] = (short)f2bf(v.w);
      *(sh4*)(Bl + row * 136 + c4 * 4) = o4;
    }
    __syncthreads();
#pragma unroll
    for (int kk = 0; kk < 4; ++kk) {
      bfrag bv = *(const bfrag*)(Bl + (w * 16 + l15) * 136 + kk * 32 + quad * 8);
#pragma unroll
      for (int mt = 0; mt < 7; ++mt) {
        bfrag av = *(const bfrag*)(Al + (mt * 16 + l15) * 136 + kk * 32 + quad * 8);
        acc[mt] = __builtin_amdgcn_mfma_f32_16x16x32_bf16(av, bv, acc[mt], 0, 0, 0);
      }
    }
    __syncthreads();
  }
  float* pb = partial + (size_t)(b * 32 + ks) * (100 * 256) + ct * 128 + w * 16 + l15;
#pragma unroll
  for (int mt = 0; mt < 7; ++mt)
#pragma unroll
    for (int r = 0; r < 4; ++r) {
      int m = mt * 16 + quad * 4 + r;
      if (m < 100) pb[(size_t)m * 256] = acc[mt][r];
    }
}

__global__ __launch_bounds__(256) void reduceA(const float* __restrict__ partial,
                                               float* __restrict__ fm) {
  int gid = blockIdx.x * 256 + threadIdx.x;
  int c = gid & 255, row = gid >> 8;
  int b = row / 100, n = row % 100;
  float s = 0.f;
#pragma unroll
  for (int ks = 0; ks < 32; ++ks)
    s += partial[((size_t)(b * 32 + ks) * 100 + n) * 256 + c];
  fm[(size_t)row * 256 + c] = s;
}

// ---------------------------------------------------------------------------
// dysep middle: wbuf rows (stride 104): [pw(100) | dw(3) | pad]
// ---------------------------------------------------------------------------
__global__ __launch_bounds__(256) void pointdw(const float* __restrict__ fm,
                                               const float* __restrict__ wbuf,
                                               float* __restrict__ point) {
  int tid = threadIdx.x;
  int b = blockIdx.y, c0 = blockIdx.x * 32;
  __shared__ float dl[100 * 33];
  for (int flat = tid; flat < 3200; flat += 256) {
    int n = flat >> 5, cl = flat & 31, c = c0 + cl;
    const float* fr = fm + (size_t)(b * 100 + n) * 256;
    const float* wr = wbuf + (size_t)(b * 100 + n) * 104;
    float x0 = (c > 0) ? fr[c - 1] : 0.f;
    float x1 = fr[c];
    float x2 = (c < 255) ? fr[c + 1] : 0.f;
    float d = wr[100] * x0 + wr[101] * x1 + wr[102] * x2;
    dl[n * 33 + cl] = fmaxf(d, 0.f);
  }
  __syncthreads();
  int cl = tid & 31, mg = tid >> 5;
  for (int m = mg; m < 100; m += 8) {
    const float4* pw4 = (const float4*)(wbuf + (size_t)(b * 100 + m) * 104);
    float a = 0.f;
#pragma unroll
    for (int n4 = 0; n4 < 25; ++n4) {
      float4 wv = pw4[n4];
      a += wv.x * dl[(n4 * 4 + 0) * 33 + cl] + wv.y * dl[(n4 * 4 + 1) * 33 + cl]
         + wv.z * dl[(n4 * 4 + 2) * 33 + cl] + wv.w * dl[(n4 * 4 + 3) * 33 + cl];
    }
    point[(size_t)(b * 100 + m) * 256 + c0 + cl] = a;
  }
}

// ---------------------------------------------------------------------------
__global__ __launch_bounds__(256) void ln2_kernel(const float* __restrict__ x,
                                                  const float* __restrict__ resid,
                                                  const float* __restrict__ g1, const float* __restrict__ b1,
                                                  const float* __restrict__ g2, const float* __restrict__ b2,
                                                  float* __restrict__ out) {
  int tid = threadIdx.x;
  int row = blockIdx.x * 4 + (tid >> 6);
  int lane = tid & 63;
  size_t base = (size_t)row * 256 + lane * 4;
  float4 v = *(const float4*)(x + base);
  float mean = wred_sum(v.x + v.y + v.z + v.w) * (1.f / 256.f);
  float d0 = v.x - mean, d1 = v.y - mean, d2 = v.z - mean, d3 = v.w - mean;
  float rs = rsqrtf(wred_sum(d0 * d0 + d1 * d1 + d2 * d2 + d3 * d3) * (1.f / 256.f) + 1e-5f);
  float4 gv = *(const float4*)(g1 + lane * 4);
  float4 bv = *(const float4*)(b1 + lane * 4);
  float4 rv = *(const float4*)(resid + base);
  float y0 = rv.x + d0 * rs * gv.x + bv.x;
  float y1 = rv.y + d1 * rs * gv.y + bv.y;
  float y2 = rv.z + d2 * rs * gv.z + bv.z;
  float y3 = rv.w + d3 * rs * gv.w + bv.w;
  float mean2 = wred_sum(y0 + y1 + y2 + y3) * (1.f / 256.f);
  float e0 = y0 - mean2, e1 = y1 - mean2, e2 = y2 - mean2, e3 = y3 - mean2;
  float rs2 = rsqrtf(wred_sum(e0 * e0 + e1 * e1 + e2 * e2 + e3 * e3) * (1.f / 256.f) + 1e-5f);
  float4 g2v = *(const float4*)(g2 + lane * 4);
  float4 b2v = *(const float4*)(b2 + lane * 4);
  float4 o;
  o.x = e0 * rs2 * g2v.x + b2v.x;
  o.y = e1 * rs2 * g2v.y + b2v.y;
  o.z = e2 * rs2 * g2v.z + b2v.z;
  o.w = e3 * rs2 * g2v.w + b2v.w;
  *(float4*)(out + base) = o;
}

__global__ __launch_bounds__(256) void ln_kernel(const float* __restrict__ x,
                                                 const float* __restrict__ res,
                                                 const float* __restrict__ g, const float* __restrict__ bb,
                                                 float* __restrict__ out, int relu,
                                                 float* __restrict__ copy2) {
  int tid = threadIdx.x;
  int row = blockIdx.x * 4 + (tid >> 6);
  int lane = tid & 63;
  size_t base = (size_t)row * 256 + lane * 4;
  float4 v = *(const float4*)(x + base);
  if (res) {
    float4 rv = *(const float4*)(res + base);
    v.x += rv.x; v.y += rv.y; v.z += rv.z; v.w += rv.w;
  }
  float mean = wred_sum(v.x + v.y + v.z + v.w) * (1.f / 256.f);
  float d0 = v.x - mean, d1 = v.y - mean, d2 = v.z - mean, d3 = v.w - mean;
  float rs = rsqrtf(wred_sum(d0 * d0 + d1 * d1 + d2 * d2 + d3 * d3) * (1.f / 256.f) + 1e-5f);
  float4 gv = *(const float4*)(g + lane * 4);
  float4 bv = *(const float4*)(bb + lane * 4);
  float4 o;
  o.x = d0 * rs * gv.x + bv.x;
  o.y = d1 * rs * gv.y + bv.y;
  o.z = d2 * rs * gv.z + bv.z;
  o.w = d3 * rs * gv.w + bv.w;
  if (relu) {
    o.x = fmaxf(o.x, 0.f); o.y = fmaxf(o.y, 0.f);
    o.z = fmaxf(o.z, 0.f); o.w = fmaxf(o.w, 0.f);
  }
  *(float4*)(out + base) = o;
  if (copy2) *(float4*)(copy2 + base) = o;
}

// ---------------------------------------------------------------------------
// MHA: one block per (head, batch). N=100, d=32.
// ---------------------------------------------------------------------------
__global__ __launch_bounds__(256) void attn_kernel(const float* __restrict__ qkv,
                                                   float* __restrict__ obuf) {
  int tid = threadIdx.x;
  int b = blockIdx.y, h = blockIdx.x;
  __shared__ float ktj[100 * 32];          // k [j][dd]
  __shared__ unsigned short vl[100 * 32];  // v bf16 [j][dd]
  __shared__ float sl[100 * 100];
  const float* base = qkv + (size_t)b * 100 * 768;
  for (int flat = tid; flat < 3200; flat += 256) {
    int j = flat >> 5, dd = flat & 31;
    ktj[j * 32 + dd] = base[(size_t)j * 768 + 256 + h * 32 + dd];
    vl[j * 32 + dd] = f2bf(base[(size_t)j * 768 + 512 + h * 32 + dd]);
  }
  __syncthreads();
  {
    int i = tid >> 1;
    int jh = (tid & 1) * 50;
    int qi = (i < 100) ? i : 0;
    const float4* q4 = (const float4*)(base + (size_t)qi * 768 + h * 32);
    float4 q[8];
#pragma unroll
    for (int d4 = 0; d4 < 8; ++d4) q[d4] = q4[d4];
    if (i < 100) {
      for (int jj = 0; jj < 50; ++jj) {
        int j = jh + jj;
        const float4* kr = (const float4*)(ktj + j * 32);
        float a = 0.f;
#pragma unroll
        for (int d4 = 0; d4 < 8; ++d4) {
          float4 kv = kr[d4];
          a += q[d4].x * kv.x + q[d4].y * kv.y + q[d4].z * kv.z + q[d4].w * kv.w;
        }
        sl[i * 100 + j] = a * 0.17677669529663687f;
      }
    }
  }
  __syncthreads();
  int w = tid >> 6, lane = tid & 63;
  for (int r = w; r < 100; r += 4) {
    float x0 = sl[r * 100 + lane];
    float x1 = (lane + 64 < 100) ? sl[r * 100 + lane + 64] : -1e30f;
    float mx = wred_max(fmaxf(x0, x1));
    float e0 = __expf(x0 - mx);
    float e1 = (lane + 64 < 100) ? __expf(x1 - mx) : 0.f;
    float inv = 1.f / wred_sum(e0 + e1);
    sl[r * 100 + lane] = e0 * inv;
    if (lane + 64 < 100) sl[r * 100 + lane + 64] = e1 * inv;
  }
  __syncthreads();
  for (int flat = tid; flat < 3200; flat += 256) {
    int i = flat >> 5, dd = flat & 31;
    float a = 0.f;
#pragma unroll 4
    for (int j = 0; j < 100; ++j) a += sl[i * 100 + j] * bf2f(vl[j * 32 + dd]);
    obuf[(size_t)(b * 100 + i) * 256 + h * 32 + dd] = a;
  }
}

// ---------------------------------------------------------------------------
// Phase E: out[b][q][hw] = sum_c mk[b][q][c] * feat[b][c][hw]
// ---------------------------------------------------------------------------
__global__ __launch_bounds__(256) void phaseE(const float* __restrict__ mk,
                                              const float* __restrict__ feat,
                                              float* __restrict__ out) {
  int tid = threadIdx.x;
  int b = blockIdx.y;
  int hw0 = blockIdx.x * 128;
  __shared__ short Al[112 * 264];
#pragma unroll
  for (int p = 0; p < 28; ++p) {
    int flat = p * 256 + tid;
    int row = flat >> 6, c4 = flat & 63;
    sh4 o4;
    if (row < 100) {
      float4 v = *(const float4*)(mk + (size_t)(b * 100 + row) * 256 + c4 * 4);
      o4[0] = (short)f2bf(v.x); o4[1] = (short)f2bf(v.y);
      o4[2] = (short)f2bf(v.z); o4[3] = (short)f2bf(v.w);
    } else {
      o4[0] = 0; o4[1] = 0; o4[2] = 0; o4[3] = 0;
    }
    *(sh4*)(Al + row * 264 + c4 * 4) = o4;
  }
  __syncthreads();
  int w = tid >> 6, lane = tid & 63, quad = lane >> 4, l15 = lane & 15;
  f32x4 acc[7][2];
#pragma unroll
  for (int mt = 0; mt < 7; ++mt)
#pragma unroll
    for (int nt = 0; nt < 2; ++nt) {
      acc[mt][nt][0] = 0.f; acc[mt][nt][1] = 0.f; acc[mt][nt][2] = 0.f; acc[mt][nt][3] = 0.f;
    }
  size_t fb = (size_t)b * 256 * 16384;
  int hwl = hw0 + w * 32 + l15;
  for (int kk = 0; kk < 8; ++kk) {
    bfrag bv[2];
#pragma unroll
    for (int nt = 0; nt < 2; ++nt) {
#pragma unroll
      for (int j = 0; j < 8; ++j) {
        float v = feat[fb + (size_t)(kk * 32 + quad * 8 + j) * 16384 + hwl + nt * 16];
        bv[nt][j] = (short)f2bf(v);
      }
    }
    bfrag av[7];
#pragma unroll
    for (int mt = 0; mt < 7; ++mt)
      av[mt] = *(const bfrag*)(Al + (mt * 16 + l15) * 264 + kk * 32 + quad * 8);
#pragma unroll
    for (int mt = 0; mt < 7; ++mt) {
      acc[mt][0] = __builtin_amdgcn_mfma_f32_16x16x32_bf16(av[mt], bv[0], acc[mt][0], 0, 0, 0);
      acc[mt][1] = __builtin_amdgcn_mfma_f32_16x16x32_bf16(av[mt], bv[1], acc[mt][1], 0, 0, 0);
    }
  }
#pragma unroll
  for (int mt = 0; mt < 7; ++mt)
#pragma unroll
    for (int nt = 0; nt < 2; ++nt)
#pragma unroll
      for (int r = 0; r < 4; ++r) {
        int m = mt * 16 + quad * 4 + r;
        if (m < 100)
          out[(size_t)(b * 100 + m) * 16384 + hw0 + w * 32 + nt * 16 + l15] = acc[mt][nt][r];
      }
}

// ---------------------------------------------------------------------------
extern "C" void kernel_launch(void* const* d_in, const int* in_sizes, int n_in,
                              void* d_out, int out_size, void* d_ws, size_t ws_size,
                              hipStream_t stream) {
  const float* feat    = (const float*)d_in[0];
  const float* prop    = (const float*)d_in[1];
  const float* maskp   = (const float*)d_in[2];
  const float* fW      = (const float*)d_in[3];
  const float* fb_     = (const float*)d_in[4];
  const float* fng     = (const float*)d_in[5];
  const float* fnb     = (const float*)d_in[6];
  const float* f_ng    = (const float*)d_in[7];
  const float* f_nb    = (const float*)d_in[8];
  const float* kW      = (const float*)d_in[9];
  const float* kb_     = (const float*)d_in[10];
  const float* kng     = (const float*)d_in[11];
  const float* knb     = (const float*)d_in[12];
  const float* k_ng    = (const float*)d_in[13];
  const float* k_nb    = (const float*)d_in[14];
  const float* aw_in   = (const float*)d_in[15];
  const float* ab_in   = (const float*)d_in[16];
  const float* aw_out  = (const float*)d_in[17];
  const float* ab_out  = (const float*)d_in[18];
  const float* s_ng    = (const float*)d_in[19];
  const float* s_nb    = (const float*)d_in[20];
  const float* w1      = (const float*)d_in[21];
  const float* b1      = (const float*)d_in[22];
  const float* w2      = (const float*)d_in[23];
  const float* b2      = (const float*)d_in[24];
  const float* ffn_ng  = (const float*)d_in[25];
  const float* ffn_nb  = (const float*)d_in[26];
  const float* cls_w   = (const float*)d_in[27];
  const float* cls_g   = (const float*)d_in[28];
  const float* cls_b   = (const float*)d_in[29];
  const float* fcclsw  = (const float*)d_in[30];
  const float* fcclsb  = (const float*)d_in[31];
  const float* mask_w  = (const float*)d_in[32];
  const float* mask_g  = (const float*)d_in[33];
  const float* mask_b  = (const float*)d_in[34];
  const float* fcmw    = (const float*)d_in[35];
  const float* fcmb    = (const float*)d_in[36];
  float* out = (float*)d_out;

  // ---- workspace: 30.46 MB total (proven-safe bound is 33.03 MB) ----
  float* ws = (float*)d_ws;
  size_t off = 0;
  unsigned short* wt = (unsigned short*)(ws + off); off += 856192;  // 1,712,384 bf16
  float* fm     = ws + off; off += 204800;
  float* bias_f = ws + off; off += 104;
  float* bias_k = ws + off; off += 104;
  float* partial = ws + off;   // union region: 8*32*100*256 = 6,553,600 floats
  float* ub = partial;
  size_t uo = 0;
  float* wb   = ub + uo; uo += 83200;   // 800 x 104
  float* pt   = ub + uo; uo += 204800;
  float* fbuf = ub + uo; uo += 204800;
  float* kkb  = ub + uo; uo += 204800;
  float* qkvb = ub + uo; uo += 614400;
  float* ob   = ub + uo; uo += 204800;
  float* mo   = ub + uo; uo += 204800;
  float* kk2  = ub + uo; uo += 204800;
  float* t1   = ub + uo; uo += 204800;
  float* objb = ub + uo; uo += 204800;
  float* t2   = ub + uo; uo += 204800;
  float* mkb  = ub + uo; uo += 204800;
  unsigned short* ffn1b = (unsigned short*)(ub + uo); uo += 409600;  // 800x2048 bf16

  // Wt sub-offsets (shorts): fW/kW are 104 rows (permuted), others N rows
  const int wt_fW = 0, wt_kW = 26624, wt_ain = 53248, wt_aout = 249856;
  const int wt_w1 = 315392, wt_w2 = 839680, wt_cls = 1363968, wt_fccls = 1429504;
  const int wt_m0 = 1450240, wt_m1 = 1515776, wt_m2 = 1581312, wt_fcm = 1646848;

  float* out_cls  = out;                       // [800][81]
  float* out_mask = out + 64800;               // [8][100][16384]
  float* out_obj  = out + 64800 + 13107200;    // [800][256]

  // ---- weight prep (transpose + bf16 + fW/kW col-permute) ----
  Prep12 p;
  const float* srcs[12] = {fW, kW, aw_in, aw_out, w1, w2, cls_w, fcclsw,
                           mask_w, mask_w + 65536, mask_w + 131072, fcmw};
  int Ks[12]    = {256, 256, 256, 256, 256, 2048, 256, 256, 256, 256, 256, 256};
  int Ns[12]    = {103, 103, 768, 256, 2048, 256, 256, 81, 256, 256, 256, 256};
  int doffs[12] = {wt_fW, wt_kW, wt_ain, wt_aout, wt_w1, wt_w2, wt_cls, wt_fccls,
                   wt_m0, wt_m1, wt_m2, wt_fcm};
  int tb = 0;
  for (int i = 0; i < 12; ++i) {
    p.s[i] = srcs[i]; p.K[i] = Ks[i]; p.N[i] = Ns[i]; p.doff[i] = doffs[i];
    p.base[i] = tb;
    tb += ((Ks[i] + 31) / 32) * ((Ns[i] + 31) / 32);
  }
  prep_w<<<tb, 256, 0, stream>>>(p, wt);
  prep_bias<<<1, 256, 0, stream>>>(fb_, kb_, bias_f, bias_k);

  // f_masked = hard(mask) @ feat^T
  phaseA<<<dim3(32, 2, 8), 512, 0, stream>>>(maskp, feat, partial);
  reduceA<<<800, 256, 0, stream>>>(partial, fm);
  // dysep 1  (partial region reused for activations from here)
  gemm_mf<0, 0><<<dim3(13, 2), 256, 0, stream>>>(prop, wt + wt_fW, bias_f, wb, 800, 256, 103, 104, 0);
  pointdw<<<dim3(8, 8), 256, 0, stream>>>(fm, wb, pt);
  ln2_kernel<<<200, 256, 0, stream>>>(pt, fm, fng, fnb, f_ng, f_nb, fbuf);
  // dysep 2
  gemm_mf<0, 0><<<dim3(13, 2), 256, 0, stream>>>(prop, wt + wt_kW, bias_k, wb, 800, 256, 103, 104, 0);
  pointdw<<<dim3(8, 8), 256, 0, stream>>>(fbuf, wb, pt);
  ln2_kernel<<<200, 256, 0, stream>>>(pt, fbuf, kng, knb, k_ng, k_nb, kkb);
  // MHA
  gemm_mf<0, 0><<<dim3(13, 12), 256, 0, stream>>>(kkb, wt + wt_ain, ab_in, qkvb, 800, 256, 768, 768, 0);
  attn_kernel<<<dim3(8, 8), 256, 0, stream>>>(qkvb, ob);
  gemm_mf<0, 0><<<dim3(13, 4), 256, 0, stream>>>(ob, wt + wt_aout, ab_out, mo, 800, 256, 256, 256, 0);
  ln_kernel<<<200, 256, 0, stream>>>(mo, kkb, s_ng, s_nb, kk2, 0, nullptr);
  // FFN
  gemm_mf<0, 1><<<dim3(13, 32), 256, 0, stream>>>(kk2, wt + wt_w1, b1, ffn1b, 800, 256, 2048, 2048, 1);
  gemm_mf<1, 0><<<dim3(13, 4), 256, 0, stream>>>(ffn1b, wt + wt_w2, b2, t1, 800, 2048, 256, 256, 0);
  ln_kernel<<<200, 256, 0, stream>>>(t1, kk2, ffn_ng, ffn_nb, objb, 0, out_obj);
  // cls head
  gemm_mf<0, 0><<<dim3(13, 4), 256, 0, stream>>>(objb, wt + wt_cls, nullptr, t1, 800, 256, 256, 256, 0);
  ln_kernel<<<200, 256, 0, stream>>>(t1, nullptr, cls_g, cls_b, t2, 1, nullptr);
  gemm_mf<0, 0><<<dim3(13, 2), 256, 0, stream>>>(t2, wt + wt_fccls, fcclsb, out_cls, 800, 256, 81, 81, 0);
  // mask head (3 layers)
  gemm_mf<0, 0><<<dim3(13, 4), 256, 0, stream>>>(objb, wt + wt_m0, nullptr, t1, 800, 256, 256, 256, 0);
  ln_kernel<<<200, 256, 0, stream>>>(t1, nullptr, mask_g, mask_b, t2, 1, nullptr);
  gemm_mf<0, 0><<<dim3(13, 4), 256, 0, stream>>>(t2, wt + wt_m1, nullptr, t1, 800, 256, 256, 256, 0);
  ln_kernel<<<200, 256, 0, stream>>>(t1, nullptr, mask_g + 256, mask_b + 256, t2, 1, nullptr);
  gemm_mf<0, 0><<<dim3(13, 4), 256, 0, stream>>>(t2, wt + wt_m2, nullptr, t1, 800, 256, 256, 256, 0);
  ln_kernel<<<200, 256, 0, stream>>>(t1, nullptr, mask_g + 512, mask_b + 512, t2, 1, nullptr);
  gemm_mf<0, 0><<<dim3(13, 4), 256, 0, stream>>>(t2, wt + wt_fcm, fcmb, mkb, 800, 256, 256, 256, 0);
  // new_mask_preds = mk @ feat
  phaseE<<<dim3(128, 8), 256, 0, stream>>>(mkb, feat, out_mask);
}